// Round 1
// baseline (190.274 us; speedup 1.0000x reference)
//
#include <hip/hip_runtime.h>
#include <hip/hip_bf16.h>

#define BB 16
#define NN 16384
#define DD 128
#define CC 32
#define CHUNKS 32
#define ROWS_PER_BLOCK (NN / CHUNKS)   // 512

// ---------------- Kernel 1: segment sums + counts ----------------
// Grid: (CHUNKS, BB), block 256.
// LDS accumulator lsum[c][j] where j is a PERMUTED d-index:
//   element d = sub*4 + k (float4 lane sub, component k) is stored at j = k*32 + sub.
// This makes every ds_add_f32 across the wave hit distinct banks (2-way alias only).
// The permutation is consistent across clusters, and the downstream gram sums over
// all d, so it never needs to be undone.
__global__ __launch_bounds__(256) void seg_sum_kernel(
    const float* __restrict__ x, const int* __restrict__ ids,
    float* __restrict__ gsums, float* __restrict__ gcounts) {
  __shared__ float lsum[CC * DD];   // 16 KB
  __shared__ float lcnt[CC];

  const int tid = threadIdx.x;
  for (int i = tid; i < CC * DD; i += 256) lsum[i] = 0.f;
  if (tid < CC) lcnt[tid] = 0.f;
  __syncthreads();

  const int b    = blockIdx.y;
  const int row0 = blockIdx.x * ROWS_PER_BLOCK;
  const int sub  = tid & 31;    // float4 index within row (0..31)
  const int rloc = tid >> 5;    // 0..7 : 8 rows per iteration

  const float4* __restrict__ x4 =
      reinterpret_cast<const float4*>(x + (size_t)b * NN * DD);
  const int* __restrict__ idrow = ids + (size_t)b * NN;

  for (int r = row0 + rloc; r < row0 + ROWS_PER_BLOCK; r += 8) {
    float4 v = x4[(size_t)r * 32 + sub];
    int cid  = idrow[r];
    float* dst = &lsum[cid * DD + sub];      // + k*32 per component
    atomicAdd(dst +  0, v.x);
    atomicAdd(dst + 32, v.y);
    atomicAdd(dst + 64, v.z);
    atomicAdd(dst + 96, v.w);
    if (sub == 0) atomicAdd(&lcnt[cid], 1.f);
  }
  __syncthreads();

  float* __restrict__ gs = gsums + (size_t)b * CC * DD;
  for (int i = tid; i < CC * DD; i += 256) atomicAdd(&gs[i], lsum[i]);
  if (tid < CC) atomicAdd(&gcounts[b * CC + tid], lcnt[tid]);
}

// ---------------- Kernel 2: means -> gram -> triu sum -> mean ----------------
// Grid: (BB), block 256. All tiny.
#define MSTR 129   // LDS row stride (129 % 32 == 1 -> consecutive-e reads conflict-free)
__global__ __launch_bounds__(256) void finish_kernel(
    const float* __restrict__ gsums, const float* __restrict__ gcounts,
    float* __restrict__ out) {
  __shared__ float mean[CC * MSTR];  // 16.5 KB
  __shared__ float cnt[CC];
  __shared__ float red[256];

  const int b = blockIdx.x;
  const int tid = threadIdx.x;

  if (tid < CC) cnt[tid] = gcounts[b * CC + tid];
  __syncthreads();

  for (int i = tid; i < CC * DD; i += 256) {
    int c = i >> 7;        // i / 128
    int d = i & 127;
    mean[c * MSTR + d] = gsums[(size_t)b * CC * DD + i] / fmaxf(cnt[c], 1.f);
  }
  __syncthreads();

  // 496 strict-upper pairs (c < e)
  float acc = 0.f;
  for (int p = tid; p < (CC * (CC - 1)) / 2; p += 256) {
    int c = 0, rem = p;
    while (rem >= (CC - 1 - c)) { rem -= (CC - 1 - c); ++c; }
    int e = c + 1 + rem;
    const float* mc = &mean[c * MSTR];
    const float* me = &mean[e * MSTR];
    float dot = 0.f;
#pragma unroll 8
    for (int d = 0; d < DD; ++d) dot += mc[d] * me[d];
    acc += fabsf(dot);
  }

  red[tid] = acc;
  __syncthreads();
  for (int s = 128; s > 0; s >>= 1) {
    if (tid < s) red[tid] += red[tid + s];
    __syncthreads();
  }

  if (tid == 0) {
    float valid = 0.f;
    for (int c = 0; c < CC; ++c) valid += (cnt[c] > 0.f) ? 1.f : 0.f;
    float denom = (valid > 1.f) ? valid * (valid - 1.f) * 0.5f : 1.f;
    atomicAdd(out, red[0] / denom * (1.0f / BB));
  }
}

extern "C" void kernel_launch(void* const* d_in, const int* in_sizes, int n_in,
                              void* d_out, int out_size, void* d_ws, size_t ws_size,
                              hipStream_t stream) {
  const float* x   = (const float*)d_in[0];
  const int*   ids = (const int*)d_in[1];
  float* out = (float*)d_out;

  float* gsums   = (float*)d_ws;                       // BB*CC*DD floats = 256 KB
  float* gcounts = gsums + (size_t)BB * CC * DD;       // BB*CC floats

  const size_t ws_bytes = ((size_t)BB * CC * DD + (size_t)BB * CC) * sizeof(float);
  hipMemsetAsync(d_ws, 0, ws_bytes, stream);
  hipMemsetAsync(d_out, 0, sizeof(float), stream);

  dim3 grid1(CHUNKS, BB);
  seg_sum_kernel<<<grid1, 256, 0, stream>>>(x, ids, gsums, gcounts);
  finish_kernel<<<BB, 256, 0, stream>>>(gsums, gcounts, out);
}